// Round 1
// baseline (40.913 us; speedup 1.0000x reference)
//
#include <hip/hip_runtime.h>

typedef unsigned short u16;
typedef unsigned int u32;
typedef __attribute__((ext_vector_type(8))) __bf16 bf16x8;
typedef __attribute__((ext_vector_type(8))) u16 u16x8;
typedef __attribute__((ext_vector_type(4))) float f32x4;

#define S_LEN 169
#define C_DIM 512
#define SP 192   // padded s-extent for wkv K-loop

// LDS layout (phase-overlaid)
#define WT_OFF  0        // wtile [48][512] bf16, swizzled            (49152 B) | phase2: kef/kvf/rff
#define XT_OFF  49152    // xtile [176][64] bf16, swizzled            (22528 B) | phase2: (part of rwkvB)
#define KE_OFF  0        // kexp  [176][16] f32                       (11264 B)
#define KVF_OFF 11264    // k*v   [176][16] f32                       (11264 B)
#define RF_OFF  22528    // r     [176][16] f32                       (11264 B)
#define KVT_OFF 33792    // kvT   [16][192] bf16, swizzled            ( 6144 B)
#define G_OFF   39936    // gate  [176][16] f32                       (11264 B)
#define RB_OFF  51200    // rwkv  [256][40] bf16 (cols16-31 zero pad) (20480 B)
#define SS_OFF  71680    // segsum [16][16] f32                       ( 1024 B)
#define OW_OFF  72704    // owT   [64][40] bf16 (cols16-31 zero pad)  ( 5120 B)
#define LDS_BYTES 77824

__device__ __forceinline__ u16 f2b(float f) {
    union { float f; u32 u; } v; v.f = f;
    u32 u = v.u;
    return (u16)((u + 0x7fffu + ((u >> 16) & 1u)) >> 16);  // RNE
}

// ---------------- kernel A: w2t[t][s] = beta[s,t] * sum_{u<=t} tw[s,255+u-t]*alpha[s,u]
__global__ __launch_bounds__(256) void w2_kernel(
    const float* __restrict__ time_w,
    const float* __restrict__ time_alpha,
    const float* __restrict__ time_beta,
    u16* __restrict__ w2t)
{
    __shared__ float tw[256];
    __shared__ float al[256];
    const int s = blockIdx.x;
    const int t = threadIdx.x;
    if (s >= S_LEN) { w2t[t * SP + s] = 0; return; }  // zero-pad columns 169..191
    tw[t] = time_w[s * 256 + t];
    al[t] = time_alpha[s * 256 + t];
    __syncthreads();
    float acc = 0.f;
    for (int u = 0; u <= t; ++u)
        acc = fmaf(tw[255 + u - t], al[u], acc);
    w2t[t * SP + s] = f2b(time_beta[s * 256 + t] * acc);
}

// ---------------- kernel B: everything else, one block per batch b
__global__ __launch_bounds__(512) void rwkv_main(
    const float* __restrict__ x,
    const float* __restrict__ key_w, const float* __restrict__ key_b,
    const float* __restrict__ value_w, const float* __restrict__ value_b,
    const float* __restrict__ recep_w, const float* __restrict__ recep_b,
    const float* __restrict__ out_w, const float* __restrict__ out_b,
    const float* __restrict__ gamma,
    const u16* __restrict__ w2t,
    float* __restrict__ out)
{
    __shared__ __align__(16) char smem[LDS_BYTES];
    const int tid  = threadIdx.x;
    const int lane = tid & 63;
    const int wid  = tid >> 6;      // 0..7
    const int q    = lane >> 4;     // quarter 0..3
    const int hs   = lane & 15;
    const int b    = blockIdx.x;
    const float* xb = x + (size_t)b * (S_LEN * C_DIM);

    // ---- stage weights: wtile[48][512] bf16, rows: 0-15 key, 16-31 value, 32-47 recep
    for (int i = tid; i < 3072; i += 512) {       // 48*64 oct-units
        int j  = i >> 6;
        int co = (i & 63) << 3;
        const float* src;
        if (j < 16)      src = key_w   + j * 512 + co;
        else if (j < 32) src = value_w + (j - 16) * 512 + co;
        else             src = recep_w + (j - 32) * 512 + co;
        float4 f0 = *(const float4*)src;
        float4 f1 = *(const float4*)(src + 4);
        u16x8 p;
        p[0]=f2b(f0.x); p[1]=f2b(f0.y); p[2]=f2b(f0.z); p[3]=f2b(f0.w);
        p[4]=f2b(f1.x); p[5]=f2b(f1.y); p[6]=f2b(f1.z); p[7]=f2b(f1.w);
        u32 off = (((u32)j << 10) + ((u32)co << 1)) ^ (((u32)(j & 7)) << 4);
        *(u16x8*)(smem + WT_OFF + off) = p;
    }

    const float kb = key_b[hs];
    const float vb = value_b[hs];
    const float rb = recep_b[hs];

    // ---- GEMM1: k,v,r = x' @ [key|value|recep]^T  (M=176pad, N=48, K=512)
    f32x4 acc0[3], acc1[3];
    #pragma unroll
    for (int n = 0; n < 3; ++n) { acc0[n] = (f32x4){0.f,0.f,0.f,0.f}; acc1[n] = (f32x4){0.f,0.f,0.f,0.f}; }
    const bool has_m1 = (wid < 3);   // 11 M-tiles over 8 waves: wid and wid+8 (wid<3)

    for (int chunk = 0; chunk < 8; ++chunk) {
        if (chunk) __syncthreads();
        // stage xtile[176][64] bf16 (swizzled); chunks 0-3 read row t-1 (channel shift), 4-7 row t
        const bool shifted = chunk < 4;
        for (int i = tid; i < 1408; i += 512) {   // 176*8 oct-units
            int r  = i >> 3;
            int co = (i & 7) << 3;
            int cg = (chunk << 6) + co;
            int tsrc = shifted ? (r - 1) : r;
            bool valid = shifted ? (r >= 1 && r <= S_LEN) : (r < S_LEN);
            u16x8 p = {0,0,0,0,0,0,0,0};
            if (valid) {
                const float* src = xb + (size_t)tsrc * C_DIM + cg;
                float4 f0 = *(const float4*)src;
                float4 f1 = *(const float4*)(src + 4);
                p[0]=f2b(f0.x); p[1]=f2b(f0.y); p[2]=f2b(f0.z); p[3]=f2b(f0.w);
                p[4]=f2b(f1.x); p[5]=f2b(f1.y); p[6]=f2b(f1.z); p[7]=f2b(f1.w);
            }
            u32 off = (((u32)r << 7) + ((u32)co << 1)) ^ (((u32)(r & 7)) << 4);
            *(u16x8*)(smem + XT_OFF + off) = p;
        }
        __syncthreads();
        #pragma unroll
        for (int ks = 0; ks < 2; ++ks) {
            int kc = ks << 5;
            bf16x8 bfr[3];
            #pragma unroll
            for (int nt = 0; nt < 3; ++nt) {
                int j = nt * 16 + hs;
                u32 col = (u32)((chunk << 6) + kc + (q << 3));
                u32 off = (((u32)j << 10) + (col << 1)) ^ (((u32)(j & 7)) << 4);
                bfr[nt] = *(const bf16x8*)(smem + WT_OFF + off);
            }
            {
                int row = wid * 16 + hs;
                u32 off = (((u32)row << 7) + ((u32)(kc + (q << 3)) << 1)) ^ (((u32)(row & 7)) << 4);
                bf16x8 afr = *(const bf16x8*)(smem + XT_OFF + off);
                acc0[0] = __builtin_amdgcn_mfma_f32_16x16x32_bf16(afr, bfr[0], acc0[0], 0,0,0);
                acc0[1] = __builtin_amdgcn_mfma_f32_16x16x32_bf16(afr, bfr[1], acc0[1], 0,0,0);
                acc0[2] = __builtin_amdgcn_mfma_f32_16x16x32_bf16(afr, bfr[2], acc0[2], 0,0,0);
            }
            if (has_m1) {
                int row = (wid + 8) * 16 + hs;
                u32 off = (((u32)row << 7) + ((u32)(kc + (q << 3)) << 1)) ^ (((u32)(row & 7)) << 4);
                bf16x8 afr = *(const bf16x8*)(smem + XT_OFF + off);
                acc1[0] = __builtin_amdgcn_mfma_f32_16x16x32_bf16(afr, bfr[0], acc1[0], 0,0,0);
                acc1[1] = __builtin_amdgcn_mfma_f32_16x16x32_bf16(afr, bfr[1], acc1[1], 0,0,0);
                acc1[2] = __builtin_amdgcn_mfma_f32_16x16x32_bf16(afr, bfr[2], acc1[2], 0,0,0);
            }
        }
    }
    __syncthreads();

    // ---- epilogue: exp(clip(k)), k*v, r  ->  LDS f32 arrays [176][16]
    float* kef = (float*)(smem + KE_OFF);
    float* kvf = (float*)(smem + KVF_OFF);
    float* rff = (float*)(smem + RF_OFF);
    #pragma unroll
    for (int m = 0; m < 2; ++m) {
        if (m == 1 && !has_m1) break;
        const f32x4* A = (m == 0) ? acc0 : acc1;
        int tb = (wid + m * 8) * 16 + (q << 2);
        float ke[4];
        #pragma unroll
        for (int rg = 0; rg < 4; ++rg) {
            float kk = A[0][rg] + kb;
            kk = fminf(fmaxf(kk, -60.f), 30.f);
            ke[rg] = __expf(kk);
        }
        #pragma unroll
        for (int rg = 0; rg < 4; ++rg) {
            int t = tb + rg;
            kef[t * 16 + hs] = ke[rg];
            kvf[t * 16 + hs] = ke[rg] * (A[1][rg] + vb);
            rff[t * 16 + hs] = A[2][rg] + rb;
        }
    }
    __syncthreads();

    // ---- scan phase: cumsum(kexp) over t per hs; produce kvT (bf16) and gate g
    float* seg = (float*)(smem + SS_OFF);
    float* g   = (float*)(smem + G_OFF);
    if (tid < 256) {
        int h = tid & 15, sg = tid >> 4;
        int t0 = sg * 11, t1 = (t0 + 11 < S_LEN) ? t0 + 11 : S_LEN;
        float s = 0.f;
        for (int t = t0; t < t1; ++t) s += kef[t * 16 + h];
        seg[sg * 16 + h] = s;
    } else {
        int i2 = tid - 256;
        // zero rwkvB pad cols 16..31 (K-pad for out-proj MFMA)
        for (int i = i2; i < 4096; i += 256) {
            int row = i >> 4, c = 16 + (i & 15);
            ((u16*)(smem + RB_OFF))[row * 40 + c] = 0;
        }
        // zero kvT tail s in [169,192)
        for (int i = i2; i < 368; i += 256) {
            int h = i & 15; int t = S_LEN + (i >> 4);
            u32 off = ((u32)(h * 384 + t * 2)) ^ (((u32)(h & 7)) << 4);
            *(u16*)(smem + KVT_OFF + off) = 0;
        }
        // stage owT[64][40] bf16 (out_w[o][c], cols 16..39 zero)
        for (int i = i2; i < 2560; i += 256) {
            int o = i / 40, c = i - o * 40;
            u16 vb16 = (c < 16) ? f2b(out_w[o * 16 + c]) : (u16)0;
            ((u16*)(smem + OW_OFF))[o * 40 + c] = vb16;
        }
    }
    __syncthreads();
    if (tid < 16) {  // exclusive prefix over 16 segments
        float run = 0.f;
        for (int sg = 0; sg < 16; ++sg) {
            float v = seg[sg * 16 + tid];
            seg[sg * 16 + tid] = run;
            run += v;
        }
    }
    __syncthreads();
    if (tid < 256) {
        int h = tid & 15, sg = tid >> 4;
        int t0 = sg * 11, t1 = (t0 + 11 < S_LEN) ? t0 + 11 : S_LEN;
        float run = seg[sg * 16 + h];
        for (int t = t0; t < t1; ++t) {
            run += kef[t * 16 + h];                       // inclusive cumsum = denom
            u32 off = ((u32)(h * 384 + t * 2)) ^ (((u32)(h & 7)) << 4);
            *(u16*)(smem + KVT_OFF + off) = f2b(kvf[t * 16 + h]);
            float rr = rff[t * 16 + h];
            float sig = 1.f / (1.f + __expf(-rr));
            g[t * 16 + h] = sig / run;
        }
    }
    __syncthreads();

    // ---- wkv: [256 t] x [192 s] @ [192 s][16 c]; A-frags straight from global w2t (L2-hot)
    f32x4 wa0 = (f32x4){0.f,0.f,0.f,0.f};
    f32x4 wa1 = (f32x4){0.f,0.f,0.f,0.f};
    #pragma unroll
    for (int s0 = 0; s0 < SP; s0 += 32) {
        int scol = s0 + (q << 3);
        u32 boff = ((u32)(hs * 384 + scol * 2)) ^ (((u32)(hs & 7)) << 4);
        bf16x8 bfr = *(const bf16x8*)(smem + KVT_OFF + boff);
        {
            int row = wid * 16 + hs;
            bf16x8 afr = *(const bf16x8*)(w2t + row * SP + scol);
            wa0 = __builtin_amdgcn_mfma_f32_16x16x32_bf16(afr, bfr, wa0, 0,0,0);
        }
        {
            int row = (wid + 8) * 16 + hs;
            bf16x8 afr = *(const bf16x8*)(w2t + row * SP + scol);
            wa1 = __builtin_amdgcn_mfma_f32_16x16x32_bf16(afr, bfr, wa1, 0,0,0);
        }
    }
    // gate and write rwkvB (bf16) cols 0..15
    #pragma unroll
    for (int m = 0; m < 2; ++m) {
        const f32x4& W = (m == 0) ? wa0 : wa1;
        int tb = (wid + m * 8) * 16 + (q << 2);
        #pragma unroll
        for (int rg = 0; rg < 4; ++rg) {
            int t = tb + rg;
            float fac = (t < S_LEN) ? g[t * 16 + hs] : 0.5f;
            ((u16*)(smem + RB_OFF))[t * 40 + hs] = f2b(W[rg] * fac);
        }
    }
    __syncthreads();

    // ---- out-proj: [256 t][32 cpad] @ [32 cpad][64 o], then (+out_b)*gamma[t]
    float obv[4];
    #pragma unroll
    for (int nt = 0; nt < 4; ++nt) obv[nt] = out_b[nt * 16 + hs];
    #pragma unroll
    for (int m = 0; m < 2; ++m) {
        int mt = wid + m * 8;
        int arow = mt * 16 + hs;
        bf16x8 afr = *(const bf16x8*)(smem + RB_OFF + (u32)(arow * 80 + (q << 4)));
        float gm[4];
        #pragma unroll
        for (int rg = 0; rg < 4; ++rg) gm[rg] = gamma[mt * 16 + (q << 2) + rg];
        #pragma unroll
        for (int nt = 0; nt < 4; ++nt) {
            int orow = nt * 16 + hs;
            bf16x8 bfr = *(const bf16x8*)(smem + OW_OFF + (u32)(orow * 80 + (q << 4)));
            f32x4 zc = (f32x4){0.f,0.f,0.f,0.f};
            f32x4 d = __builtin_amdgcn_mfma_f32_16x16x32_bf16(afr, bfr, zc, 0,0,0);
            #pragma unroll
            for (int rg = 0; rg < 4; ++rg) {
                int t = mt * 16 + (q << 2) + rg;
                out[(size_t)b * 16384 + (size_t)t * 64 + nt * 16 + hs] = (d[rg] + obv[nt]) * gm[rg];
            }
        }
    }
}

extern "C" void kernel_launch(void* const* d_in, const int* in_sizes, int n_in,
                              void* d_out, int out_size, void* d_ws, size_t ws_size,
                              hipStream_t stream) {
    const float* x          = (const float*)d_in[0];
    const float* time_w     = (const float*)d_in[1];
    const float* time_alpha = (const float*)d_in[2];
    const float* time_beta  = (const float*)d_in[3];
    const float* time_gamma = (const float*)d_in[4];
    const float* key_w      = (const float*)d_in[5];
    const float* key_b      = (const float*)d_in[6];
    const float* value_w    = (const float*)d_in[7];
    const float* value_b    = (const float*)d_in[8];
    const float* recep_w    = (const float*)d_in[9];
    const float* recep_b    = (const float*)d_in[10];
    const float* out_w      = (const float*)d_in[11];
    const float* out_b      = (const float*)d_in[12];
    u16* w2t = (u16*)d_ws;   // [256][192] bf16 = 98304 B

    w2_kernel<<<192, 256, 0, stream>>>(time_w, time_alpha, time_beta, w2t);
    rwkv_main<<<256, 512, 0, stream>>>(x, key_w, key_b, value_w, value_b,
                                       recep_w, recep_b, out_w, out_b,
                                       time_gamma, w2t, (float*)d_out);
}

// Round 2
// 38.121 us; speedup vs baseline: 1.0733x; 1.0733x over previous
//
#include <hip/hip_runtime.h>

typedef unsigned short u16;
typedef unsigned int u32;
typedef __attribute__((ext_vector_type(8))) __bf16 bf16x8;
typedef __attribute__((ext_vector_type(4))) float f32x4;

#define S_LEN 169
#define C_DIM 512
#define SP 192   // padded s-extent for wkv K-loop

// LDS layout (phase-overlaid)
// phase 1 (GEMM1): WT [48][512]bf16 swz (49152) | XT0 [176][64]bf16 swz (22528) | XT1 (22528)
// phase 2 (scan):  KE/KVF/RF [176][16]f32 | KVT [16][192]bf16 swz | G [176][16]f32 | RB [256][40]bf16 | SS | OW
#define WT_OFF  0
#define XT0_OFF 49152
#define XT1_OFF 71680
#define KE_OFF  0
#define KVF_OFF 11264
#define RF_OFF  22528
#define KVT_OFF 33792
#define G_OFF   39936
#define RB_OFF  51200    // ends 71680
#define SS_OFF  71680    // 1024 B (overlays XT1, dead by then)
#define OW_OFF  72704    // owT [64][40] bf16, ends 77824
#define LDS_BYTES 94208

// ---------------- kernel A: w2t[t][s] = beta[s,t] * sum_{u<=t} tw[s,255+u-t]*alpha[s,u]
// 4-way split of the u-range per t (depth 64 instead of 256)
__global__ __launch_bounds__(1024) void w2_kernel(
    const float* __restrict__ time_w,
    const float* __restrict__ time_alpha,
    const float* __restrict__ time_beta,
    __bf16* __restrict__ w2t)
{
    __shared__ float tw[256];
    __shared__ float al[256];
    __shared__ float part[4][256];
    const int s = blockIdx.x;
    const int t = threadIdx.x & 255;
    const int p = threadIdx.x >> 8;
    if (s >= S_LEN) {                      // zero-pad columns 169..191
        if (p == 0) w2t[t * SP + s] = (__bf16)0.f;
        return;
    }
    if (p == 0) { tw[t] = time_w[s * 256 + t]; al[t] = time_alpha[s * 256 + t]; }
    __syncthreads();
    const int u0 = p << 6;
    const int u1 = (u0 + 64 < t + 1) ? (u0 + 64) : (t + 1);
    float acc = 0.f;
    for (int u = u0; u < u1; ++u)
        acc = fmaf(tw[255 + u - t], al[u], acc);
    part[p][t] = acc;
    __syncthreads();
    if (p == 0)
        w2t[t * SP + s] = (__bf16)(time_beta[s * 256 + t] *
                                   (part[0][t] + part[1][t] + part[2][t] + part[3][t]));
}

// ---------------- kernel B: everything else, one block per batch b
__global__ __launch_bounds__(512) void rwkv_main(
    const float* __restrict__ x,
    const float* __restrict__ key_w, const float* __restrict__ key_b,
    const float* __restrict__ value_w, const float* __restrict__ value_b,
    const float* __restrict__ recep_w, const float* __restrict__ recep_b,
    const float* __restrict__ out_w, const float* __restrict__ out_b,
    const float* __restrict__ gamma,
    const __bf16* __restrict__ w2t,
    float* __restrict__ out)
{
    __shared__ __align__(16) char smem[LDS_BYTES];
    const int tid  = threadIdx.x;
    const int lane = tid & 63;
    const int wid  = tid >> 6;      // 0..7
    const int q    = lane >> 4;     // quarter 0..3
    const int hs   = lane & 15;
    const int b    = blockIdx.x;
    const float* xb = x + (size_t)b * (S_LEN * C_DIM);

    // ---- stage weights: wtile[48][512] bf16, rows: 0-15 key, 16-31 value, 32-47 recep
    for (int i = tid; i < 3072; i += 512) {       // 48*64 oct-units
        int j  = i >> 6;
        int co = (i & 63) << 3;
        const float* src;
        if (j < 16)      src = key_w   + j * 512 + co;
        else if (j < 32) src = value_w + (j - 16) * 512 + co;
        else             src = recep_w + (j - 32) * 512 + co;
        float4 f0 = *(const float4*)src;
        float4 f1 = *(const float4*)(src + 4);
        bf16x8 p;
        p[0]=(__bf16)f0.x; p[1]=(__bf16)f0.y; p[2]=(__bf16)f0.z; p[3]=(__bf16)f0.w;
        p[4]=(__bf16)f1.x; p[5]=(__bf16)f1.y; p[6]=(__bf16)f1.z; p[7]=(__bf16)f1.w;
        u32 off = (((u32)j << 10) + ((u32)co << 1)) ^ (((u32)(j & 7)) << 4);
        *(bf16x8*)(smem + WT_OFF + off) = p;
    }

    const float kb = key_b[hs];
    const float vb = value_b[hs];
    const float rb = recep_b[hs];

    // ---- GEMM1: k,v,r = x' @ [key|value|recep]^T  (M=176pad, N=48, K=512)
    // reg-staged double buffer: issue next chunk's loads before MFMA, convert+write after.
    f32x4 acc0[3], acc1[3];
    #pragma unroll
    for (int n = 0; n < 3; ++n) { acc0[n] = (f32x4){0.f,0.f,0.f,0.f}; acc1[n] = (f32x4){0.f,0.f,0.f,0.f}; }
    const bool has_m1 = (wid < 3);   // 11 M-tiles over 8 waves: wid and wid+8 (wid<3)

    float4 pf[3][2];
    int pv[3];

    auto ldchunk = [&](int chunk) {
        const bool shifted = chunk < 4;   // chunks 0-3: cols 0-255 read row t-1 (channel shift)
        #pragma unroll
        for (int it = 0; it < 3; ++it) {
            int i = tid + (it << 9);
            pv[it] = 0;
            if (i < 1408) {               // 176*8 oct-units
                int r = i >> 3;
                int tsrc = shifted ? (r - 1) : r;
                bool valid = shifted ? (r >= 1 && r <= S_LEN) : (r < S_LEN);
                pv[it] = 1;
                if (valid) {
                    const float* src = xb + (size_t)tsrc * C_DIM + (chunk << 6) + ((i & 7) << 3);
                    pf[it][0] = *(const float4*)src;
                    pf[it][1] = *(const float4*)(src + 4);
                    pv[it] = 2;
                }
            }
        }
    };

    auto cvtwrite = [&](u32 base) {
        #pragma unroll
        for (int it = 0; it < 3; ++it) {
            int i = tid + (it << 9);
            if (i < 1408 && pv[it]) {
                int r = i >> 3, co = (i & 7) << 3;
                bf16x8 p = {(__bf16)0.f,(__bf16)0.f,(__bf16)0.f,(__bf16)0.f,
                            (__bf16)0.f,(__bf16)0.f,(__bf16)0.f,(__bf16)0.f};
                if (pv[it] == 2) {
                    p[0]=(__bf16)pf[it][0].x; p[1]=(__bf16)pf[it][0].y;
                    p[2]=(__bf16)pf[it][0].z; p[3]=(__bf16)pf[it][0].w;
                    p[4]=(__bf16)pf[it][1].x; p[5]=(__bf16)pf[it][1].y;
                    p[6]=(__bf16)pf[it][1].z; p[7]=(__bf16)pf[it][1].w;
                }
                u32 off = (((u32)r << 7) + ((u32)co << 1)) ^ (((u32)(r & 7)) << 4);
                *(bf16x8*)(smem + base + off) = p;
            }
        }
    };

    auto mfma_chunk = [&](int chunk, u32 xbase) {
        #pragma unroll
        for (int ks = 0; ks < 2; ++ks) {
            int kc = ks << 5;
            bf16x8 bfr[3];
            #pragma unroll
            for (int nt = 0; nt < 3; ++nt) {
                int j = nt * 16 + hs;
                u32 col = (u32)((chunk << 6) + kc + (q << 3));
                u32 off = (((u32)j << 10) + (col << 1)) ^ (((u32)(j & 7)) << 4);
                bfr[nt] = *(const bf16x8*)(smem + WT_OFF + off);
            }
            {
                int row = wid * 16 + hs;
                u32 off = (((u32)row << 7) + ((u32)(kc + (q << 3)) << 1)) ^ (((u32)(row & 7)) << 4);
                bf16x8 afr = *(const bf16x8*)(smem + xbase + off);
                acc0[0] = __builtin_amdgcn_mfma_f32_16x16x32_bf16(afr, bfr[0], acc0[0], 0,0,0);
                acc0[1] = __builtin_amdgcn_mfma_f32_16x16x32_bf16(afr, bfr[1], acc0[1], 0,0,0);
                acc0[2] = __builtin_amdgcn_mfma_f32_16x16x32_bf16(afr, bfr[2], acc0[2], 0,0,0);
            }
            if (has_m1) {
                int row = (wid + 8) * 16 + hs;
                u32 off = (((u32)row << 7) + ((u32)(kc + (q << 3)) << 1)) ^ (((u32)(row & 7)) << 4);
                bf16x8 afr = *(const bf16x8*)(smem + xbase + off);
                acc1[0] = __builtin_amdgcn_mfma_f32_16x16x32_bf16(afr, bfr[0], acc1[0], 0,0,0);
                acc1[1] = __builtin_amdgcn_mfma_f32_16x16x32_bf16(afr, bfr[1], acc1[1], 0,0,0);
                acc1[2] = __builtin_amdgcn_mfma_f32_16x16x32_bf16(afr, bfr[2], acc1[2], 0,0,0);
            }
        }
    };

    ldchunk(0);
    cvtwrite(XT0_OFF);
    __syncthreads();
    #pragma unroll
    for (int chunk = 0; chunk < 8; ++chunk) {
        const u32 cur = (chunk & 1) ? XT1_OFF : XT0_OFF;
        const u32 nxt = (chunk & 1) ? XT0_OFF : XT1_OFF;
        if (chunk < 7) ldchunk(chunk + 1);   // issue loads early; MFMA below hides latency
        mfma_chunk(chunk, cur);
        if (chunk < 7) cvtwrite(nxt);        // vmcnt wait lands here, after MFMA
        __syncthreads();
    }

    // ---- epilogue: exp(clip(k)), k*v, r  ->  LDS f32 arrays [176][16]
    float* kef = (float*)(smem + KE_OFF);
    float* kvf = (float*)(smem + KVF_OFF);
    float* rff = (float*)(smem + RF_OFF);
    #pragma unroll
    for (int m = 0; m < 2; ++m) {
        if (m == 1 && !has_m1) break;
        const f32x4* A = (m == 0) ? acc0 : acc1;
        int tb = (wid + m * 8) * 16 + (q << 2);
        float ke[4];
        #pragma unroll
        for (int rg = 0; rg < 4; ++rg) {
            float kk = A[0][rg] + kb;
            kk = fminf(fmaxf(kk, -60.f), 30.f);
            ke[rg] = __expf(kk);
        }
        #pragma unroll
        for (int rg = 0; rg < 4; ++rg) {
            int t = tb + rg;
            kef[t * 16 + hs] = ke[rg];
            kvf[t * 16 + hs] = ke[rg] * (A[1][rg] + vb);
            rff[t * 16 + hs] = A[2][rg] + rb;
        }
    }
    __syncthreads();

    // ---- scan phase: cumsum(kexp) over t per hs; produce kvT (bf16) and gate g
    float* seg = (float*)(smem + SS_OFF);
    float* g   = (float*)(smem + G_OFF);
    if (tid < 256) {
        int h = tid & 15, sg = tid >> 4;
        int t0 = sg * 11, t1 = (t0 + 11 < S_LEN) ? t0 + 11 : S_LEN;
        float s = 0.f;
        for (int t = t0; t < t1; ++t) s += kef[t * 16 + h];
        seg[sg * 16 + h] = s;
    } else {
        int i2 = tid - 256;
        // zero rwkvB pad cols 16..31 (K-pad for out-proj MFMA)
        for (int i = i2; i < 4096; i += 256) {
            int row = i >> 4, c = 16 + (i & 15);
            ((__bf16*)(smem + RB_OFF))[row * 40 + c] = (__bf16)0.f;
        }
        // zero kvT tail s in [169,192)
        for (int i = i2; i < 368; i += 256) {
            int h = i & 15; int t = S_LEN + (i >> 4);
            u32 off = ((u32)(h * 384 + t * 2)) ^ (((u32)(h & 7)) << 4);
            *(__bf16*)(smem + KVT_OFF + off) = (__bf16)0.f;
        }
        // stage owT[64][40] bf16 (out_w[o][c], cols 16..39 zero)
        for (int i = i2; i < 2560; i += 256) {
            int o = i / 40, c = i - o * 40;
            ((__bf16*)(smem + OW_OFF))[o * 40 + c] = (c < 16) ? (__bf16)out_w[o * 16 + c] : (__bf16)0.f;
        }
    }
    __syncthreads();
    if (tid < 16) {  // exclusive prefix over 16 segments
        float run = 0.f;
        for (int sg = 0; sg < 16; ++sg) {
            float v = seg[sg * 16 + tid];
            seg[sg * 16 + tid] = run;
            run += v;
        }
    }
    __syncthreads();
    if (tid < 256) {
        int h = tid & 15, sg = tid >> 4;
        int t0 = sg * 11, t1 = (t0 + 11 < S_LEN) ? t0 + 11 : S_LEN;
        float run = seg[sg * 16 + h];
        for (int t = t0; t < t1; ++t) {
            run += kef[t * 16 + h];                       // inclusive cumsum = denom
            u32 off = ((u32)(h * 384 + t * 2)) ^ (((u32)(h & 7)) << 4);
            *(__bf16*)(smem + KVT_OFF + off) = (__bf16)kvf[t * 16 + h];
            float rr = rff[t * 16 + h];
            float sig = 1.f / (1.f + __expf(-rr));
            g[t * 16 + h] = sig / run;
        }
    }
    __syncthreads();

    // ---- wkv: [256 t] x [192 s] @ [192 s][16 c]; A-frags straight from global w2t (L2-hot)
    f32x4 wa0 = (f32x4){0.f,0.f,0.f,0.f};
    f32x4 wa1 = (f32x4){0.f,0.f,0.f,0.f};
    #pragma unroll
    for (int s0 = 0; s0 < SP; s0 += 32) {
        int scol = s0 + (q << 3);
        u32 boff = ((u32)(hs * 384 + scol * 2)) ^ (((u32)(hs & 7)) << 4);
        bf16x8 bfr = *(const bf16x8*)(smem + KVT_OFF + boff);
        {
            int row = wid * 16 + hs;
            bf16x8 afr = *(const bf16x8*)(w2t + row * SP + scol);
            wa0 = __builtin_amdgcn_mfma_f32_16x16x32_bf16(afr, bfr, wa0, 0,0,0);
        }
        {
            int row = (wid + 8) * 16 + hs;
            bf16x8 afr = *(const bf16x8*)(w2t + row * SP + scol);
            wa1 = __builtin_amdgcn_mfma_f32_16x16x32_bf16(afr, bfr, wa1, 0,0,0);
        }
    }
    // gate and write rwkvB (bf16) cols 0..15
    #pragma unroll
    for (int m = 0; m < 2; ++m) {
        const f32x4& W = (m == 0) ? wa0 : wa1;
        int tb = (wid + m * 8) * 16 + (q << 2);
        #pragma unroll
        for (int rg = 0; rg < 4; ++rg) {
            int t = tb + rg;
            float fac = (t < S_LEN) ? g[t * 16 + hs] : 0.5f;
            ((__bf16*)(smem + RB_OFF))[t * 40 + hs] = (__bf16)(W[rg] * fac);
        }
    }
    __syncthreads();

    // ---- out-proj: [256 t][32 cpad] @ [32 cpad][64 o], then (+out_b)*gamma[t]
    float obv[4];
    #pragma unroll
    for (int nt = 0; nt < 4; ++nt) obv[nt] = out_b[nt * 16 + hs];
    #pragma unroll
    for (int m = 0; m < 2; ++m) {
        int mt = wid + m * 8;
        int arow = mt * 16 + hs;
        bf16x8 afr = *(const bf16x8*)(smem + RB_OFF + (u32)(arow * 80 + (q << 4)));
        float gm[4];
        #pragma unroll
        for (int rg = 0; rg < 4; ++rg) gm[rg] = gamma[mt * 16 + (q << 2) + rg];
        #pragma unroll
        for (int nt = 0; nt < 4; ++nt) {
            int orow = nt * 16 + hs;
            bf16x8 bfr = *(const bf16x8*)(smem + OW_OFF + (u32)(orow * 80 + (q << 4)));
            f32x4 zc = (f32x4){0.f,0.f,0.f,0.f};
            f32x4 d = __builtin_amdgcn_mfma_f32_16x16x32_bf16(afr, bfr, zc, 0,0,0);
            #pragma unroll
            for (int rg = 0; rg < 4; ++rg) {
                int t = mt * 16 + (q << 2) + rg;
                out[(size_t)b * 16384 + (size_t)t * 64 + nt * 16 + hs] = (d[rg] + obv[nt]) * gm[rg];
            }
        }
    }
}

extern "C" void kernel_launch(void* const* d_in, const int* in_sizes, int n_in,
                              void* d_out, int out_size, void* d_ws, size_t ws_size,
                              hipStream_t stream) {
    const float* x          = (const float*)d_in[0];
    const float* time_w     = (const float*)d_in[1];
    const float* time_alpha = (const float*)d_in[2];
    const float* time_beta  = (const float*)d_in[3];
    const float* time_gamma = (const float*)d_in[4];
    const float* key_w      = (const float*)d_in[5];
    const float* key_b      = (const float*)d_in[6];
    const float* value_w    = (const float*)d_in[7];
    const float* value_b    = (const float*)d_in[8];
    const float* recep_w    = (const float*)d_in[9];
    const float* recep_b    = (const float*)d_in[10];
    const float* out_w      = (const float*)d_in[11];
    const float* out_b      = (const float*)d_in[12];
    __bf16* w2t = (__bf16*)d_ws;   // [256][192] bf16 = 98304 B

    w2_kernel<<<192, 1024, 0, stream>>>(time_w, time_alpha, time_beta, w2t);
    rwkv_main<<<256, 512, 0, stream>>>(x, key_w, key_b, value_w, value_b,
                                       recep_w, recep_b, out_w, out_b,
                                       time_gamma, w2t, (float*)d_out);
}

// Round 3
// 38.055 us; speedup vs baseline: 1.0751x; 1.0017x over previous
//
#include <hip/hip_runtime.h>

typedef unsigned short u16;
typedef unsigned int u32;
typedef __attribute__((ext_vector_type(8))) __bf16 bf16x8;
typedef __attribute__((ext_vector_type(4))) float f32x4;

#define S_LEN 169
#define C_DIM 512
#define SP 192   // padded s-extent for wkv K-loop

// LDS layout (phase-overlaid)
// phase 1 (GEMM1): WT [48][512]bf16 swz (49152) | XT0 [176][64]bf16 swz (22528) | XT1 (22528)
// phase 2 (scan):  KE/KVF/RF [176][16]f32 | KVT [16][192]bf16 swz | G | RB | SS | OW
#define WT_OFF  0
#define XT0_OFF 49152
#define XT1_OFF 71680
#define KE_OFF  0
#define KVF_OFF 11264
#define RF_OFF  22528
#define KVT_OFF 33792
#define G_OFF   39936
#define RB_OFF  51200    // ends 71680
#define SS_OFF  71680    // seg [16][16] f32 (overlays XT1, dead by then)
#define OW_OFF  72704    // owT [64][40] bf16, ends 77824
#define LDS_BYTES 94208

// LDS-write → barrier without draining vmcnt (keeps global loads in flight)
#define LGKM_BAR() asm volatile("s_waitcnt lgkmcnt(0)\n\ts_barrier" ::: "memory")

// ---------------- kernel A: w2t[t][s] = beta[s,t] * sum_{u<=t} tw[s,255+u-t]*alpha[s,u]
__global__ __launch_bounds__(1024) void w2_kernel(
    const float* __restrict__ time_w,
    const float* __restrict__ time_alpha,
    const float* __restrict__ time_beta,
    __bf16* __restrict__ w2t)
{
    __shared__ float tw[256];
    __shared__ float al[256];
    __shared__ float part[4][256];
    const int s = blockIdx.x;
    const int t = threadIdx.x & 255;
    const int p = threadIdx.x >> 8;
    if (s >= S_LEN) {                      // zero-pad columns 169..191
        if (p == 0) w2t[t * SP + s] = (__bf16)0.f;
        return;
    }
    if (p == 0) { tw[t] = time_w[s * 256 + t]; al[t] = time_alpha[s * 256 + t]; }
    __syncthreads();
    const int u0 = p << 6;
    const int u1 = (u0 + 64 < t + 1) ? (u0 + 64) : (t + 1);
    float acc = 0.f;
    for (int u = u0; u < u1; ++u)
        acc = fmaf(tw[255 + u - t], al[u], acc);
    part[p][t] = acc;
    __syncthreads();
    if (p == 0)
        w2t[t * SP + s] = (__bf16)(time_beta[s * 256 + t] *
                                   (part[0][t] + part[1][t] + part[2][t] + part[3][t]));
}

// ---------------- kernel B: everything else, one block per batch b
__global__ __launch_bounds__(512) void rwkv_main(
    const float* __restrict__ x,
    const float* __restrict__ key_w, const float* __restrict__ key_b,
    const float* __restrict__ value_w, const float* __restrict__ value_b,
    const float* __restrict__ recep_w, const float* __restrict__ recep_b,
    const float* __restrict__ out_w, const float* __restrict__ out_b,
    const float* __restrict__ gamma,
    const __bf16* __restrict__ w2t,
    float* __restrict__ out)
{
    __shared__ __align__(16) char smem[LDS_BYTES];
    const int tid  = threadIdx.x;
    const int lane = tid & 63;
    const int wid  = tid >> 6;      // 0..7
    const int q    = lane >> 4;     // quarter 0..3
    const int hs   = lane & 15;
    const int b    = blockIdx.x;
    const float* xb = x + (size_t)b * (S_LEN * C_DIM);

    // ---- stage weights: wtile[48][512] bf16, rows: 0-15 key, 16-31 value, 32-47 recep
    for (int i = tid; i < 3072; i += 512) {       // 48*64 oct-units
        int j  = i >> 6;
        int co = (i & 63) << 3;
        const float* src;
        if (j < 16)      src = key_w   + j * 512 + co;
        else if (j < 32) src = value_w + (j - 16) * 512 + co;
        else             src = recep_w + (j - 32) * 512 + co;
        float4 f0 = *(const float4*)src;
        float4 f1 = *(const float4*)(src + 4);
        bf16x8 p;
        p[0]=(__bf16)f0.x; p[1]=(__bf16)f0.y; p[2]=(__bf16)f0.z; p[3]=(__bf16)f0.w;
        p[4]=(__bf16)f1.x; p[5]=(__bf16)f1.y; p[6]=(__bf16)f1.z; p[7]=(__bf16)f1.w;
        u32 off = (((u32)j << 10) + ((u32)co << 1)) ^ (((u32)(j & 7)) << 4);
        *(bf16x8*)(smem + WT_OFF + off) = p;
    }

    const float kb = key_b[hs];
    const float vb = value_b[hs];
    const float rb = recep_b[hs];

    // ---- GEMM1: k,v,r = x' @ [key|value|recep]^T  (M=176pad, N=48, K=512)
    // 2-chunk-deep register prefetch; loads stay in flight across LGKM-only barriers.
    f32x4 acc0[3], acc1[3];
    #pragma unroll
    for (int n = 0; n < 3; ++n) { acc0[n] = (f32x4){0.f,0.f,0.f,0.f}; acc1[n] = (f32x4){0.f,0.f,0.f,0.f}; }
    const bool has_m1 = (wid < 3);   // 11 M-tiles over 8 waves: wid and wid+8 (wid<3)

    float4 pfA[3][2]; int pvA[3];
    float4 pfB[3][2]; int pvB[3];

    auto ldchunk = [&](int chunk, float4 (&pf)[3][2], int (&pv)[3]) {
        const bool shifted = chunk < 4;   // chunks 0-3: cols 0-255 read row t-1 (channel shift)
        #pragma unroll
        for (int it = 0; it < 3; ++it) {
            int i = tid + (it << 9);
            pv[it] = 0;
            if (i < 1408) {               // 176*8 oct-units
                int r = i >> 3;
                int tsrc = shifted ? (r - 1) : r;
                bool valid = shifted ? (r >= 1 && r <= S_LEN) : (r < S_LEN);
                pv[it] = 1;
                if (valid) {
                    const float* src = xb + (size_t)tsrc * C_DIM + (chunk << 6) + ((i & 7) << 3);
                    pf[it][0] = *(const float4*)src;
                    pf[it][1] = *(const float4*)(src + 4);
                    pv[it] = 2;
                }
            }
        }
    };

    auto cvtwrite = [&](u32 base, float4 (&pf)[3][2], int (&pv)[3]) {
        #pragma unroll
        for (int it = 0; it < 3; ++it) {
            int i = tid + (it << 9);
            if (i < 1408 && pv[it]) {
                int r = i >> 3, co = (i & 7) << 3;
                bf16x8 p = {(__bf16)0.f,(__bf16)0.f,(__bf16)0.f,(__bf16)0.f,
                            (__bf16)0.f,(__bf16)0.f,(__bf16)0.f,(__bf16)0.f};
                if (pv[it] == 2) {
                    p[0]=(__bf16)pf[it][0].x; p[1]=(__bf16)pf[it][0].y;
                    p[2]=(__bf16)pf[it][0].z; p[3]=(__bf16)pf[it][0].w;
                    p[4]=(__bf16)pf[it][1].x; p[5]=(__bf16)pf[it][1].y;
                    p[6]=(__bf16)pf[it][1].z; p[7]=(__bf16)pf[it][1].w;
                }
                u32 off = (((u32)r << 7) + ((u32)co << 1)) ^ (((u32)(r & 7)) << 4);
                *(bf16x8*)(smem + base + off) = p;
            }
        }
    };

    auto mfma_chunk = [&](int chunk, u32 xbase) {
        #pragma unroll
        for (int ks = 0; ks < 2; ++ks) {
            int kc = ks << 5;
            bf16x8 bfr[3];
            #pragma unroll
            for (int nt = 0; nt < 3; ++nt) {
                int j = nt * 16 + hs;
                u32 col = (u32)((chunk << 6) + kc + (q << 3));
                u32 off = (((u32)j << 10) + (col << 1)) ^ (((u32)(j & 7)) << 4);
                bfr[nt] = *(const bf16x8*)(smem + WT_OFF + off);
            }
            {
                int row = wid * 16 + hs;
                u32 off = (((u32)row << 7) + ((u32)(kc + (q << 3)) << 1)) ^ (((u32)(row & 7)) << 4);
                bf16x8 afr = *(const bf16x8*)(smem + xbase + off);
                acc0[0] = __builtin_amdgcn_mfma_f32_16x16x32_bf16(afr, bfr[0], acc0[0], 0,0,0);
                acc0[1] = __builtin_amdgcn_mfma_f32_16x16x32_bf16(afr, bfr[1], acc0[1], 0,0,0);
                acc0[2] = __builtin_amdgcn_mfma_f32_16x16x32_bf16(afr, bfr[2], acc0[2], 0,0,0);
            }
            if (has_m1) {
                int row = (wid + 8) * 16 + hs;
                u32 off = (((u32)row << 7) + ((u32)(kc + (q << 3)) << 1)) ^ (((u32)(row & 7)) << 4);
                bf16x8 afr = *(const bf16x8*)(smem + xbase + off);
                acc1[0] = __builtin_amdgcn_mfma_f32_16x16x32_bf16(afr, bfr[0], acc1[0], 0,0,0);
                acc1[1] = __builtin_amdgcn_mfma_f32_16x16x32_bf16(afr, bfr[1], acc1[1], 0,0,0);
                acc1[2] = __builtin_amdgcn_mfma_f32_16x16x32_bf16(afr, bfr[2], acc1[2], 0,0,0);
            }
        }
    };

    // prologue: chunk0 staged; chunks 1 (A) and 2 (B) in flight
    ldchunk(0, pfA, pvA);
    cvtwrite(XT0_OFF, pfA, pvA);
    ldchunk(1, pfA, pvA);
    ldchunk(2, pfB, pvB);
    LGKM_BAR();

    #pragma unroll
    for (int chunk = 0; chunk < 8; ++chunk) {
        const u32 cur = (chunk & 1) ? XT1_OFF : XT0_OFF;
        const u32 nxt = (chunk & 1) ? XT0_OFF : XT1_OFF;
        mfma_chunk(chunk, cur);
        if (chunk < 7) {            // odd chunks live in A, even in B
            if (chunk & 1) cvtwrite(nxt, pfB, pvB);
            else           cvtwrite(nxt, pfA, pvA);
        }
        LGKM_BAR();
        if (chunk < 5) {
            if (chunk & 1) ldchunk(chunk + 3, pfB, pvB);
            else           ldchunk(chunk + 3, pfA, pvA);
        }
    }

    // ---- epilogue: exp(clip(k)), k*v, r  ->  LDS f32 arrays [176][16]
    float* kef = (float*)(smem + KE_OFF);
    float* kvf = (float*)(smem + KVF_OFF);
    float* rff = (float*)(smem + RF_OFF);
    #pragma unroll
    for (int m = 0; m < 2; ++m) {
        if (m == 1 && !has_m1) break;
        const f32x4* A = (m == 0) ? acc0 : acc1;
        int tb = (wid + m * 8) * 16 + (q << 2);
        float ke[4];
        #pragma unroll
        for (int rg = 0; rg < 4; ++rg) {
            float kk = A[0][rg] + kb;
            kk = fminf(fmaxf(kk, -60.f), 30.f);
            ke[rg] = __expf(kk);
        }
        #pragma unroll
        for (int rg = 0; rg < 4; ++rg) {
            int t = tb + rg;
            kef[t * 16 + hs] = ke[rg];
            kvf[t * 16 + hs] = ke[rg] * (A[1][rg] + vb);
            rff[t * 16 + hs] = A[2][rg] + rb;
        }
    }
    __syncthreads();

    // ---- scan phase: segment sums (waves 0-3) | stage owT/zero pads (waves 4-7)
    float* seg = (float*)(smem + SS_OFF);
    float* g   = (float*)(smem + G_OFF);
    if (tid < 256) {
        int h = tid & 15, sg = tid >> 4;
        int t0 = sg * 11, t1 = (t0 + 11 < S_LEN) ? t0 + 11 : S_LEN;
        float s = 0.f;
        for (int t = t0; t < t1; ++t) s += kef[t * 16 + h];
        seg[sg * 16 + h] = s;
    } else {
        int i2 = tid - 256;
        // zero rwkvB pad cols 16..31 (K-pad for out-proj MFMA)
        for (int i = i2; i < 4096; i += 256) {
            int row = i >> 4, c = 16 + (i & 15);
            ((__bf16*)(smem + RB_OFF))[row * 40 + c] = (__bf16)0.f;
        }
        // zero kvT tail s in [169,192)
        for (int i = i2; i < 368; i += 256) {
            int h2 = i & 15; int t = S_LEN + (i >> 4);
            u32 off = ((u32)(h2 * 384 + t * 2)) ^ (((u32)(h2 & 7)) << 4);
            *(__bf16*)(smem + KVT_OFF + off) = (__bf16)0.f;
        }
        // stage owT[64][40] bf16 (out_w[o][c], cols 16..39 zero)
        for (int i = i2; i < 2560; i += 256) {
            int o = i / 40, c = i - o * 40;
            ((__bf16*)(smem + OW_OFF))[o * 40 + c] = (c < 16) ? (__bf16)out_w[o * 16 + c] : (__bf16)0.f;
        }
    }
    __syncthreads();

    // ---- per-thread redundant exclusive prefix (broadcast reads, parallel),
    //      then inclusive cumsum + kvT (bf16) + gate in one pass
    if (tid < 256) {
        int h = tid & 15, sg = tid >> 4;
        float run = 0.f;
        for (int s2 = 0; s2 < sg; ++s2) run += seg[s2 * 16 + h];
        int t0 = sg * 11, t1 = (t0 + 11 < S_LEN) ? t0 + 11 : S_LEN;
        for (int t = t0; t < t1; ++t) {
            run += kef[t * 16 + h];                       // inclusive cumsum = denom
            u32 off = ((u32)(h * 384 + t * 2)) ^ (((u32)(h & 7)) << 4);
            *(__bf16*)(smem + KVT_OFF + off) = (__bf16)kvf[t * 16 + h];
            float rr = rff[t * 16 + h];
            g[t * 16 + h] = 1.f / ((1.f + __expf(-rr)) * run);   // sigmoid(r)/denom
        }
    }
    __syncthreads();

    // ---- wkv: [256 t] x [192 s] @ [192 s][16 c]; A-frags straight from global w2t (L2-hot)
    f32x4 wa0 = (f32x4){0.f,0.f,0.f,0.f};
    f32x4 wa1 = (f32x4){0.f,0.f,0.f,0.f};
    #pragma unroll
    for (int s0 = 0; s0 < SP; s0 += 32) {
        int scol = s0 + (q << 3);
        u32 boff = ((u32)(hs * 384 + scol * 2)) ^ (((u32)(hs & 7)) << 4);
        bf16x8 bfr = *(const bf16x8*)(smem + KVT_OFF + boff);
        {
            int row = wid * 16 + hs;
            bf16x8 afr = *(const bf16x8*)(w2t + row * SP + scol);
            wa0 = __builtin_amdgcn_mfma_f32_16x16x32_bf16(afr, bfr, wa0, 0,0,0);
        }
        {
            int row = (wid + 8) * 16 + hs;
            bf16x8 afr = *(const bf16x8*)(w2t + row * SP + scol);
            wa1 = __builtin_amdgcn_mfma_f32_16x16x32_bf16(afr, bfr, wa1, 0,0,0);
        }
    }
    // gate and write rwkvB (bf16) cols 0..15
    #pragma unroll
    for (int m = 0; m < 2; ++m) {
        const f32x4& W = (m == 0) ? wa0 : wa1;
        int tb = (wid + m * 8) * 16 + (q << 2);
        #pragma unroll
        for (int rg = 0; rg < 4; ++rg) {
            int t = tb + rg;
            float fac = (t < S_LEN) ? g[t * 16 + hs] : 0.5f;
            ((__bf16*)(smem + RB_OFF))[t * 40 + hs] = (__bf16)(W[rg] * fac);
        }
    }
    __syncthreads();

    // ---- out-proj: [256 t][32 cpad] @ [32 cpad][64 o], then (+out_b)*gamma[t]
    float obv[4];
    #pragma unroll
    for (int nt = 0; nt < 4; ++nt) obv[nt] = out_b[nt * 16 + hs];
    #pragma unroll
    for (int m = 0; m < 2; ++m) {
        int mt = wid + m * 8;
        int arow = mt * 16 + hs;
        bf16x8 afr = *(const bf16x8*)(smem + RB_OFF + (u32)(arow * 80 + (q << 4)));
        float gm[4];
        #pragma unroll
        for (int rg = 0; rg < 4; ++rg) gm[rg] = gamma[mt * 16 + (q << 2) + rg];
        #pragma unroll
        for (int nt = 0; nt < 4; ++nt) {
            int orow = nt * 16 + hs;
            bf16x8 bfr = *(const bf16x8*)(smem + OW_OFF + (u32)(orow * 80 + (q << 4)));
            f32x4 zc = (f32x4){0.f,0.f,0.f,0.f};
            f32x4 d = __builtin_amdgcn_mfma_f32_16x16x32_bf16(afr, bfr, zc, 0,0,0);
            #pragma unroll
            for (int rg = 0; rg < 4; ++rg) {
                int t = mt * 16 + (q << 2) + rg;
                out[(size_t)b * 16384 + (size_t)t * 64 + nt * 16 + hs] = (d[rg] + obv[nt]) * gm[rg];
            }
        }
    }
}

extern "C" void kernel_launch(void* const* d_in, const int* in_sizes, int n_in,
                              void* d_out, int out_size, void* d_ws, size_t ws_size,
                              hipStream_t stream) {
    const float* x          = (const float*)d_in[0];
    const float* time_w     = (const float*)d_in[1];
    const float* time_alpha = (const float*)d_in[2];
    const float* time_beta  = (const float*)d_in[3];
    const float* time_gamma = (const float*)d_in[4];
    const float* key_w      = (const float*)d_in[5];
    const float* key_b      = (const float*)d_in[6];
    const float* value_w    = (const float*)d_in[7];
    const float* value_b    = (const float*)d_in[8];
    const float* recep_w    = (const float*)d_in[9];
    const float* recep_b    = (const float*)d_in[10];
    const float* out_w      = (const float*)d_in[11];
    const float* out_b      = (const float*)d_in[12];
    __bf16* w2t = (__bf16*)d_ws;   // [256][192] bf16 = 98304 B

    w2_kernel<<<192, 1024, 0, stream>>>(time_w, time_alpha, time_beta, w2t);
    rwkv_main<<<256, 512, 0, stream>>>(x, key_w, key_b, value_w, value_b,
                                       recep_w, recep_b, out_w, out_b,
                                       time_gamma, w2t, (float*)d_out);
}